// Round 12
// baseline (338.857 us; speedup 1.0000x reference)
//
#include <hip/hip_runtime.h>
#include <hip/hip_bf16.h>

// ---------------------------------------------------------------------------
// EdgeClassifier: 2-layer GraphSAGE (mean agg) + edge-scoring MLP.
// Full bf16 data path (fp32 accumulate).
//   prep: deg atomics + x->bf16 (R12: ea conversion dropped — net-negative,
//     prep paid 77MB to save edge_mlp 25.6MB on a latency-bound kernel)
//   CSR build: scan + XCD-group-partitioned counting-sort place (R9 proven)
//   per layer: csr_agg_half (R12: 32-ch halves routed to XCD groups via
//     blockIdx&7 so each XCD's gather working set is 3.2MB < 4MiB L2;
//     same %8 heuristic fill_csr_xcd validated) -> dense_mfma (K=128 GEMM)
//   edge_mlp_pipe: R7/R11-proven — edges=A register-gathered, weight
//     B-fragments in registers (VGPR 80 / 6 waves/SIMD), 2-stage pipeline,
//     ea read fp32 + packed in-register. R10 lesson: never cap VGPR below
//     the pipeline's needs (spill catastrophe).
// N=50000, E=800000, C=64, EDGE_DIM=16, MLP K=144 padded to 160.
// ---------------------------------------------------------------------------

#define C 64
#define KP 168          // edge-MLP weight LDS row stride (shorts)
#define SK 136          // dense LDS K-stride (shorts)
#define TILE_E 64
#define WSHIFT 12       // 4096-node dst windows for the fill partition

typedef short short8 __attribute__((ext_vector_type(8)));
typedef float f32x4 __attribute__((ext_vector_type(4)));

__device__ __forceinline__ unsigned short f2bf(float f) {
    unsigned int u = __float_as_uint(f);
    return (unsigned short)((u + 0x7FFFu + ((u >> 16) & 1u)) >> 16);   // RNE
}
__device__ __forceinline__ unsigned int pack2(float lo, float hi) {
    return (unsigned int)f2bf(lo) | ((unsigned int)f2bf(hi) << 16);
}
__device__ __forceinline__ float bflo(unsigned int u) { return __uint_as_float(u << 16); }
__device__ __forceinline__ float bfhi(unsigned int u) { return __uint_as_float(u & 0xFFFF0000u); }

// ---- prep: degree atomics + x->bf16 ----------------------------------------
__global__ void prep(const int* __restrict__ dst, int* __restrict__ degi,
                     const float* __restrict__ x, unsigned short* __restrict__ xB,
                     int E, int nx8) {
    int i = blockIdx.x * blockDim.x + threadIdx.x;
    if (i < E) atomicAdd(&degi[dst[i]], 1);
    if (i < nx8) {
        const float4* p = (const float4*)(x + (size_t)i * 8);
        float4 a = p[0], b = p[1];
        uint4 o;
        o.x = pack2(a.x, a.y); o.y = pack2(a.z, a.w);
        o.z = pack2(b.x, b.y); o.w = pack2(b.z, b.w);
        *(uint4*)(xB + (size_t)i * 8) = o;
    }
}

// ---- CSR build --------------------------------------------------------------
__global__ __launch_bounds__(256) void scan_partial(const int* __restrict__ degi,
        int* __restrict__ rowptr, int* __restrict__ partials, int N) {
    __shared__ int sWs[4];
    int t = threadIdx.x, b = blockIdx.x;
    int g0 = b * 1024 + t * 4;
    int v0 = (g0 + 0 < N) ? degi[g0 + 0] : 0;
    int v1 = (g0 + 1 < N) ? degi[g0 + 1] : 0;
    int v2 = (g0 + 2 < N) ? degi[g0 + 2] : 0;
    int v3 = (g0 + 3 < N) ? degi[g0 + 3] : 0;
    int tsum = v0 + v1 + v2 + v3;
    int lane = t & 63, w = t >> 6;
    int incl = tsum;
    #pragma unroll
    for (int m = 1; m < 64; m <<= 1) {
        int y = __shfl_up(incl, m, 64);
        if (lane >= m) incl += y;
    }
    if (lane == 63) sWs[w] = incl;
    __syncthreads();
    int wprefix = 0;
    for (int i = 0; i < w; ++i) wprefix += sWs[i];
    int run = wprefix + incl - tsum;
    if (g0 + 0 < N) rowptr[g0 + 0] = run; run += v0;
    if (g0 + 1 < N) rowptr[g0 + 1] = run; run += v1;
    if (g0 + 2 < N) rowptr[g0 + 2] = run; run += v2;
    if (g0 + 3 < N) rowptr[g0 + 3] = run;
    if (t == 255) partials[b] = wprefix + incl;
}

__global__ __launch_bounds__(256) void scan_add_fused(int* __restrict__ rowptr,
        const int* __restrict__ partials, int* __restrict__ cursor,
        const int* __restrict__ degi, float* __restrict__ deg_inv,
        int N, int E, int nb) {
    __shared__ int sOff[64];
    int t = threadIdx.x;
    if (t < 64) {
        int v = (t < nb) ? partials[t] : 0;
        int incl = v;
        #pragma unroll
        for (int m = 1; m < 64; m <<= 1) {
            int y = __shfl_up(incl, m, 64);
            if (t >= m) incl += y;
        }
        sOff[t] = incl - v;
    }
    __syncthreads();
    int i = blockIdx.x * 256 + t;
    if (i < N) {
        int r = rowptr[i] + sOff[i >> 10];
        rowptr[i] = r;
        cursor[i] = r;
        deg_inv[i] = 1.0f / fmaxf((float)degi[i], 1.0f);
    }
    if (i == 0) rowptr[N] = E;
}

// XCD-group-partitioned place (R9 proven: killed the write amplification).
__global__ __launch_bounds__(256) void fill_csr_xcd(const int* __restrict__ src,
        const int* __restrict__ dst, int* __restrict__ cursor,
        int* __restrict__ eSrc, int E) {
    int g = blockIdx.x & 7;
    int tid = (blockIdx.x >> 3) * 256 + threadIdx.x;
    int stride = (gridDim.x >> 3) * 256;
    for (int e = tid; e < E; e += stride) {
        int d = dst[e];
        if (((d >> WSHIFT) & 7) == g) {
            int pos = atomicAdd(&cursor[d], 1);
            eSrc[pos] = src[e];
        }
    }
}

// ---- CSR gather mean-aggregation, XCD-sliced channel halves ----------------
// Block handles 4 nodes for ONE 32-ch half: g=blockIdx&7; half = g>>2 (XCD
// groups 0-3 -> ch[0,32), 4-7 -> ch[32,64)), nodes from (b>>3)*16+(g&3)*4.
// Per wave: 16 edge-slots x 4 ch-groups of 8 (uint4 loads), butterfly over
// slots. Each aggB half-row = one 64B line written by 4 contiguous lanes.
__global__ __launch_bounds__(256) void csr_agg_half(const unsigned short* __restrict__ fB,
        const int* __restrict__ rowptr, const int* __restrict__ eSrc,
        const float* __restrict__ deg_inv, unsigned short* __restrict__ aggB, int N) {
    int b = blockIdx.x;
    int g = b & 7;
    int node = (b >> 3) * 16 + (g & 3) * 4 + (threadIdx.x >> 6);
    if (node >= N) return;
    int lane = threadIdx.x & 63;
    int slot = lane >> 2, cg = lane & 3;
    int choff = (g >> 2) * 32 + cg * 8;
    int row = rowptr[node], end = rowptr[node + 1];
    float a[8] = {0.f, 0.f, 0.f, 0.f, 0.f, 0.f, 0.f, 0.f};
    for (int j0 = row; j0 < end; j0 += 16) {
        int j = j0 + slot;
        if (j < end) {
            int s = eSrc[j];
            uint4 v = *(const uint4*)(fB + (size_t)s * C + choff);
            a[0] += bflo(v.x); a[1] += bfhi(v.x);
            a[2] += bflo(v.y); a[3] += bfhi(v.y);
            a[4] += bflo(v.z); a[5] += bfhi(v.z);
            a[6] += bflo(v.w); a[7] += bfhi(v.w);
        }
    }
    #pragma unroll
    for (int m = 4; m < 64; m <<= 1)
        #pragma unroll
        for (int k = 0; k < 8; ++k)
            a[k] += __shfl_xor(a[k], m, 64);
    if (slot == 0) {
        float di = deg_inv[node];
        uint4 o;
        o.x = pack2(a[0] * di, a[1] * di);
        o.y = pack2(a[2] * di, a[3] * di);
        o.z = pack2(a[4] * di, a[5] * di);
        o.w = pack2(a[6] * di, a[7] * di);
        *(uint4*)(aggB + (size_t)node * C + choff) = o;
    }
}

// ---- dense SAGE layer via MFMA: h = relu([agg|x] @ [Wl;Wr] + bl) -----------
__global__ __launch_bounds__(256) void dense_mfma(
        const unsigned short* __restrict__ aB, const unsigned short* __restrict__ xB,
        const float* __restrict__ Wl, const float* __restrict__ Wr,
        const float* __restrict__ bl, unsigned short* __restrict__ hOut, int N) {
    __shared__ unsigned short sW[C * SK];
    __shared__ unsigned short sAB[C * SK];
    int t = threadIdx.x;
    int lane = t & 63, w = t >> 6;
    int l15 = lane & 15, quad = lane >> 4;
    int n0 = blockIdx.x * 64;

    for (int i = t; i < 128 * C; i += 256) {
        int k = i >> 6, n = i & 63;
        float v = (k < C) ? Wl[k * C + n] : Wr[(k - C) * C + n];
        sW[n * SK + k] = f2bf(v);
    }
    for (int i = t; i < 64 * 16; i += 256) {
        int r = i >> 4, ch = i & 15;
        int node = n0 + r;
        uint4 v = {0u, 0u, 0u, 0u};
        if (node < N)
            v = (ch < 8) ? *(const uint4*)(aB + (size_t)node * C + ch * 8)
                         : *(const uint4*)(xB + (size_t)node * C + (ch - 8) * 8);
        *(uint4*)&sAB[r * SK + ch * 8] = v;
    }
    __syncthreads();

    short8 bW[4][4];
    #pragma unroll
    for (int t4 = 0; t4 < 4; ++t4)
        #pragma unroll
        for (int kc = 0; kc < 4; ++kc)
            bW[t4][kc] = *(const short8*)&sW[(t4 * 16 + l15) * SK + kc * 32 + quad * 8];
    float blr[4];
    #pragma unroll
    for (int t4 = 0; t4 < 4; ++t4) blr[t4] = bl[t4 * 16 + l15];

    f32x4 acc[4] = {{0.f, 0.f, 0.f, 0.f}, {0.f, 0.f, 0.f, 0.f},
                    {0.f, 0.f, 0.f, 0.f}, {0.f, 0.f, 0.f, 0.f}};
    #pragma unroll
    for (int kc = 0; kc < 4; ++kc) {
        short8 a = *(const short8*)&sAB[(w * 16 + l15) * SK + kc * 32 + quad * 8];
        #pragma unroll
        for (int t4 = 0; t4 < 4; ++t4)
            acc[t4] = __builtin_amdgcn_mfma_f32_16x16x32_bf16(a, bW[t4][kc], acc[t4], 0, 0, 0);
    }
    __syncthreads();

    #pragma unroll
    for (int t4 = 0; t4 < 4; ++t4)
        #pragma unroll
        for (int r = 0; r < 4; ++r) {
            int rl = w * 16 + quad * 4 + r;
            sW[rl * 72 + t4 * 16 + l15] = f2bf(fmaxf(acc[t4][r] + blr[t4], 0.f));
        }
    __syncthreads();
    for (int i = t; i < 64 * 8; i += 256) {
        int r = i >> 3, c8 = i & 7;
        int node = n0 + r;
        if (node < N)
            *(uint4*)(hOut + (size_t)node * C + c8 * 8) = *(const uint4*)&sW[r * 72 + c8 * 8];
    }
}

// ---- edge MLP: bf16 MFMA, register A-gather, 2-stage pipeline (R7 proven) --
__device__ __forceinline__ void gather_rows(const unsigned short* __restrict__ hB,
        const float* __restrict__ ea, int s, int d, int idxc, int quad,
        uint4& u0, uint4& u1, uint4& u2, uint4& u3, uint4& u4) {
    const uint4* ps = (const uint4*)(hB + (size_t)s * C);
    const uint4* pd = (const uint4*)(hB + (size_t)d * C);
    u0 = ps[quad];
    u1 = ps[4 + quad];
    u2 = pd[quad];
    u3 = pd[4 + quad];
    u4.x = 0u; u4.y = 0u; u4.z = 0u; u4.w = 0u;
    if (quad < 2) {
        const float4* pe = (const float4*)(ea + (size_t)idxc * 16 + quad * 8);
        float4 f0 = pe[0], f1 = pe[1];
        u4.x = pack2(f0.x, f0.y); u4.y = pack2(f0.z, f0.w);
        u4.z = pack2(f1.x, f1.y); u4.w = pack2(f1.z, f1.w);
    }
}

__global__ __launch_bounds__(256) void edge_mlp_pipe(
        const unsigned short* __restrict__ hB, const int* __restrict__ src,
        const int* __restrict__ dst, const float* __restrict__ ea,
        const float* __restrict__ Wm1, const float* __restrict__ bm1,
        const float* __restrict__ Wm2, const float* __restrict__ bm2,
        float* __restrict__ out, int E, int nTiles) {
    __shared__ unsigned short sW[C * KP];     // Wm1^T bf16, K zero-padded to 160
    int t = threadIdx.x;
    int lane = t & 63, w = t >> 6;
    int l15 = lane & 15, quad = lane >> 4;

    for (int i = t; i < C * 3; i += 256) {
        int r = i / 3, cc = 144 + (i % 3) * 8;
        uint4 z = {0u, 0u, 0u, 0u};
        *(uint4*)&sW[r * KP + cc] = z;
    }
    for (int i = t; i < 144 * C; i += 256) {
        int k = i >> 6, n = i & 63;
        sW[n * KP + k] = f2bf(Wm1[i]);
    }
    __syncthreads();

    short8 bW[4][5];
    #pragma unroll
    for (int t4 = 0; t4 < 4; ++t4)
        #pragma unroll
        for (int kc = 0; kc < 5; ++kc)
            bW[t4][kc] = *(const short8*)&sW[(t4 * 16 + l15) * KP + kc * 32 + quad * 8];
    float bmr[4], w2r[4];
    #pragma unroll
    for (int t4 = 0; t4 < 4; ++t4) {
        int j = t4 * 16 + l15;
        bmr[t4] = bm1[j];
        w2r[t4] = Wm2[j];
    }
    float bb = bm2[0];

    int stride = gridDim.x;
    int lbase = w * 16 + l15;

    int tile = blockIdx.x;
    int idxc = min(tile * TILE_E + lbase, E - 1);
    int s = src[idxc], d = dst[idxc];
    int tileN = tile + stride;
    int idxNc = (tileN < nTiles) ? min(tileN * TILE_E + lbase, E - 1) : idxc;
    int sN = src[idxNc], dN = dst[idxNc];
    uint4 cu0, cu1, cu2, cu3, cu4;
    gather_rows(hB, ea, s, d, idxc, quad, cu0, cu1, cu2, cu3, cu4);

    while (true) {
        bool hasNext = (tileN < nTiles);
        uint4 nu0, nu1, nu2, nu3, nu4;
        gather_rows(hB, ea, sN, dN, idxNc, quad, nu0, nu1, nu2, nu3, nu4);
        int tileNN = tileN + stride;
        int idxNNc = (tileNN < nTiles) ? min(tileNN * TILE_E + lbase, E - 1) : idxNc;
        int sNN = src[idxNNc], dNN = dst[idxNNc];

        short8 a0 = *(short8*)&cu0, a1 = *(short8*)&cu1, a2 = *(short8*)&cu2,
               a3 = *(short8*)&cu3, a4 = *(short8*)&cu4;
        f32x4 acc[4] = {{0.f, 0.f, 0.f, 0.f}, {0.f, 0.f, 0.f, 0.f},
                        {0.f, 0.f, 0.f, 0.f}, {0.f, 0.f, 0.f, 0.f}};
        #pragma unroll
        for (int t4 = 0; t4 < 4; ++t4) {
            acc[t4] = __builtin_amdgcn_mfma_f32_16x16x32_bf16(a0, bW[t4][0], acc[t4], 0, 0, 0);
            acc[t4] = __builtin_amdgcn_mfma_f32_16x16x32_bf16(a1, bW[t4][1], acc[t4], 0, 0, 0);
            acc[t4] = __builtin_amdgcn_mfma_f32_16x16x32_bf16(a2, bW[t4][2], acc[t4], 0, 0, 0);
            acc[t4] = __builtin_amdgcn_mfma_f32_16x16x32_bf16(a3, bW[t4][3], acc[t4], 0, 0, 0);
            acc[t4] = __builtin_amdgcn_mfma_f32_16x16x32_bf16(a4, bW[t4][4], acc[t4], 0, 0, 0);
        }

        float sres[4];
        #pragma unroll
        for (int r = 0; r < 4; ++r) {
            float v = 0.f;
            #pragma unroll
            for (int t4 = 0; t4 < 4; ++t4)
                v += fmaxf(acc[t4][r] + bmr[t4], 0.f) * w2r[t4];
            #pragma unroll
            for (int m = 1; m < 16; m <<= 1)
                v += __shfl_xor(v, m, 16);
            sres[r] = v;
        }
        if (l15 == 0) {
            int e0 = tile * TILE_E;
            #pragma unroll
            for (int r = 0; r < 4; ++r) {
                int e = e0 + w * 16 + quad * 4 + r;
                if (e < E) out[e] = sres[r] + bb;
            }
        }

        if (!hasNext) break;
        tile = tileN; tileN = tileNN;
        idxc = idxNc; idxNc = idxNNc;
        s = sN; sN = sNN; d = dN; dN = dNN;
        cu0 = nu0; cu1 = nu1; cu2 = nu2; cu3 = nu3; cu4 = nu4;
    }
}

// ---------------------------------------------------------------------------
extern "C" void kernel_launch(void* const* d_in, const int* in_sizes, int n_in,
                              void* d_out, int out_size, void* d_ws, size_t ws_size,
                              hipStream_t stream) {
    const float* x   = (const float*)d_in[0];
    const int*   ei  = (const int*)d_in[1];
    const float* ea  = (const float*)d_in[2];
    const float* W1l = (const float*)d_in[3];
    const float* b1l = (const float*)d_in[4];
    const float* W1r = (const float*)d_in[5];
    const float* W2l = (const float*)d_in[6];
    const float* b2l = (const float*)d_in[7];
    const float* W2r = (const float*)d_in[8];
    const float* Wm1 = (const float*)d_in[9];
    const float* bm1 = (const float*)d_in[10];
    const float* Wm2 = (const float*)d_in[11];
    const float* bm2 = (const float*)d_in[12];
    float* out = (float*)d_out;

    const int N = in_sizes[0] / C;
    const int E = in_sizes[1] / 2;
    const int* src = ei;
    const int* dst = ei + E;

    char* wsb = (char*)d_ws;
    int npad = (N + 1023) & ~1023;
    float* deg_inv = (float*)wsb;                wsb += (size_t)npad * 4;
    unsigned short* xB   = (unsigned short*)wsb; wsb += (size_t)npad * C * 2;
    unsigned short* h1B  = (unsigned short*)wsb; wsb += (size_t)npad * C * 2;
    unsigned short* h2B  = (unsigned short*)wsb; wsb += (size_t)npad * C * 2;
    unsigned short* aggB = (unsigned short*)wsb; wsb += (size_t)npad * C * 2;
    int* degi    = (int*)wsb;                    wsb += (size_t)npad * 4;
    int* rowptr  = (int*)wsb;                    wsb += (size_t)(npad + 64) * 4;
    int* cursor  = (int*)wsb;                    wsb += (size_t)npad * 4;
    int* eSrc    = (int*)wsb;                    wsb += (size_t)E * 4;
    int* partials = (int*)wsb;                   wsb += 64 * 4;

    int tpb = 256;
    int nb = (N + 1023) / 1024;
    int nx8 = N * C / 8;

    // CSR build + x convert
    hipMemsetAsync(degi, 0, (size_t)N * sizeof(int), stream);
    int prepN = (E > nx8) ? E : nx8;
    prep<<<(prepN + tpb - 1) / tpb, tpb, 0, stream>>>(dst, degi, x, xB, E, nx8);
    scan_partial<<<nb, tpb, 0, stream>>>(degi, rowptr, partials, N);
    scan_add_fused<<<(N + tpb - 1) / tpb, tpb, 0, stream>>>(rowptr, partials, cursor,
            degi, deg_inv, N, E, nb);
    fill_csr_xcd<<<1024, tpb, 0, stream>>>(src, dst, cursor, eSrc, E);

    // layer 1
    int aggGrid = 8 * ((N + 15) / 16);
    csr_agg_half<<<aggGrid, tpb, 0, stream>>>(xB, rowptr, eSrc, deg_inv, aggB, N);
    dense_mfma<<<(N + 63) / 64, tpb, 0, stream>>>(aggB, xB, W1l, W1r, b1l, h1B, N);

    // layer 2
    csr_agg_half<<<aggGrid, tpb, 0, stream>>>(h1B, rowptr, eSrc, deg_inv, aggB, N);
    dense_mfma<<<(N + 63) / 64, tpb, 0, stream>>>(aggB, h1B, W2l, W2r, b2l, h2B, N);

    // edge MLP (pipelined, R7 variant, ea fp32 direct)
    int nTiles = (E + TILE_E - 1) / TILE_E;
    int grid = nTiles < 2048 ? nTiles : 2048;
    edge_mlp_pipe<<<grid, tpb, 0, stream>>>(h2B, src, dst, ea,
            Wm1, bm1, Wm2, bm2, out, E, nTiles);
}

// Round 13
// 299.699 us; speedup vs baseline: 1.1307x; 1.1307x over previous
//
#include <hip/hip_runtime.h>
#include <hip/hip_bf16.h>

// ---------------------------------------------------------------------------
// EdgeClassifier: 2-layer GraphSAGE (mean agg) + edge-scoring MLP.
// Full bf16 data path (fp32 accumulate). R13 = R11 exact revert (best: 303us)
// + fill grid 2048. R12 lessons: eaB is a measured WIN for the latency-bound
// edge MLP (FETCH 67.5 vs 85 MB, 53 vs 64 us); %8 XCD slicing helps exclusive
// WRITE ownership (fill_csr) but NOT read-side gather locality (csr_agg_half
// regressed ~38us).
//   prep: deg atomics + ea->bf16 + x->bf16
//   CSR build: scan + XCD-group-partitioned counting-sort place (R9 proven)
//   per layer: csr_agg_bf16 (full-row CSR gather) -> dense_mfma (K=128 GEMM)
//   edge_mlp_pipe: R7-proven — edges=A register-gathered, weight B-frags in
//     registers (VGPR 80 / 6 waves/SIMD), 2-stage pipeline. R10 lesson: never
//     cap VGPR below the pipeline's needs (spill catastrophe).
// N=50000, E=800000, C=64, EDGE_DIM=16, MLP K=144 padded to 160.
// ---------------------------------------------------------------------------

#define C 64
#define KP 168          // edge-MLP weight LDS row stride (shorts)
#define SK 136          // dense LDS K-stride (shorts)
#define TILE_E 64
#define WSHIFT 12       // 4096-node dst windows for the fill partition

typedef short short8 __attribute__((ext_vector_type(8)));
typedef float f32x4 __attribute__((ext_vector_type(4)));

__device__ __forceinline__ unsigned short f2bf(float f) {
    unsigned int u = __float_as_uint(f);
    return (unsigned short)((u + 0x7FFFu + ((u >> 16) & 1u)) >> 16);   // RNE
}
__device__ __forceinline__ unsigned int pack2(float lo, float hi) {
    return (unsigned int)f2bf(lo) | ((unsigned int)f2bf(hi) << 16);
}
__device__ __forceinline__ float bflo(unsigned int u) { return __uint_as_float(u << 16); }
__device__ __forceinline__ float bfhi(unsigned int u) { return __uint_as_float(u & 0xFFFF0000u); }

// ---- prep: degree atomics + ea->bf16 + x->bf16, one kernel -----------------
__global__ void prep(const int* __restrict__ dst, int* __restrict__ degi,
                     const float* __restrict__ ea, unsigned short* __restrict__ eaB,
                     const float* __restrict__ x, unsigned short* __restrict__ xB,
                     int E, int nx8, int doEa) {
    int i = blockIdx.x * blockDim.x + threadIdx.x;
    if (i < E) atomicAdd(&degi[dst[i]], 1);
    if (doEa && i < 2 * E) {
        const float4* p = (const float4*)(ea + (size_t)i * 8);
        float4 a = p[0], b = p[1];
        uint4 o;
        o.x = pack2(a.x, a.y); o.y = pack2(a.z, a.w);
        o.z = pack2(b.x, b.y); o.w = pack2(b.z, b.w);
        *(uint4*)(eaB + (size_t)i * 8) = o;
    }
    if (i < nx8) {
        const float4* p = (const float4*)(x + (size_t)i * 8);
        float4 a = p[0], b = p[1];
        uint4 o;
        o.x = pack2(a.x, a.y); o.y = pack2(a.z, a.w);
        o.z = pack2(b.x, b.y); o.w = pack2(b.z, b.w);
        *(uint4*)(xB + (size_t)i * 8) = o;
    }
}

// ---- CSR build --------------------------------------------------------------
__global__ __launch_bounds__(256) void scan_partial(const int* __restrict__ degi,
        int* __restrict__ rowptr, int* __restrict__ partials, int N) {
    __shared__ int sWs[4];
    int t = threadIdx.x, b = blockIdx.x;
    int g0 = b * 1024 + t * 4;
    int v0 = (g0 + 0 < N) ? degi[g0 + 0] : 0;
    int v1 = (g0 + 1 < N) ? degi[g0 + 1] : 0;
    int v2 = (g0 + 2 < N) ? degi[g0 + 2] : 0;
    int v3 = (g0 + 3 < N) ? degi[g0 + 3] : 0;
    int tsum = v0 + v1 + v2 + v3;
    int lane = t & 63, w = t >> 6;
    int incl = tsum;
    #pragma unroll
    for (int m = 1; m < 64; m <<= 1) {
        int y = __shfl_up(incl, m, 64);
        if (lane >= m) incl += y;
    }
    if (lane == 63) sWs[w] = incl;
    __syncthreads();
    int wprefix = 0;
    for (int i = 0; i < w; ++i) wprefix += sWs[i];
    int run = wprefix + incl - tsum;
    if (g0 + 0 < N) rowptr[g0 + 0] = run; run += v0;
    if (g0 + 1 < N) rowptr[g0 + 1] = run; run += v1;
    if (g0 + 2 < N) rowptr[g0 + 2] = run; run += v2;
    if (g0 + 3 < N) rowptr[g0 + 3] = run;
    if (t == 255) partials[b] = wprefix + incl;
}

__global__ __launch_bounds__(256) void scan_add_fused(int* __restrict__ rowptr,
        const int* __restrict__ partials, int* __restrict__ cursor,
        const int* __restrict__ degi, float* __restrict__ deg_inv,
        int N, int E, int nb) {
    __shared__ int sOff[64];
    int t = threadIdx.x;
    if (t < 64) {
        int v = (t < nb) ? partials[t] : 0;
        int incl = v;
        #pragma unroll
        for (int m = 1; m < 64; m <<= 1) {
            int y = __shfl_up(incl, m, 64);
            if (t >= m) incl += y;
        }
        sOff[t] = incl - v;
    }
    __syncthreads();
    int i = blockIdx.x * 256 + t;
    if (i < N) {
        int r = rowptr[i] + sOff[i >> 10];
        rowptr[i] = r;
        cursor[i] = r;
        deg_inv[i] = 1.0f / fmaxf((float)degi[i], 1.0f);
    }
    if (i == 0) rowptr[N] = E;
}

// XCD-group-partitioned place (R9 proven: killed the write amplification).
__global__ __launch_bounds__(256) void fill_csr_xcd(const int* __restrict__ src,
        const int* __restrict__ dst, int* __restrict__ cursor,
        int* __restrict__ eSrc, int E) {
    int g = blockIdx.x & 7;
    int tid = (blockIdx.x >> 3) * 256 + threadIdx.x;
    int stride = (gridDim.x >> 3) * 256;
    for (int e = tid; e < E; e += stride) {
        int d = dst[e];
        if (((d >> WSHIFT) & 7) == g) {
            int pos = atomicAdd(&cursor[d], 1);
            eSrc[pos] = src[e];
        }
    }
}

// ---- CSR gather mean-aggregation, bf16 in/out (fp32 acc) -------------------
__global__ __launch_bounds__(256) void csr_agg_bf16(const unsigned short* __restrict__ fB,
        const int* __restrict__ rowptr, const int* __restrict__ eSrc,
        const float* __restrict__ deg_inv, unsigned short* __restrict__ aggB, int N) {
    int node = blockIdx.x * 4 + (threadIdx.x >> 6);
    if (node >= N) return;
    int lane = threadIdx.x & 63;
    int s8 = lane >> 3, ci = lane & 7;
    int row = rowptr[node], end = rowptr[node + 1];
    float a[8] = {0.f, 0.f, 0.f, 0.f, 0.f, 0.f, 0.f, 0.f};
    int j = row;
    for (; j + 16 <= end; j += 16) {
        int sA = eSrc[j + s8];
        int sB = eSrc[j + 8 + s8];
        uint4 vA = *(const uint4*)(fB + (size_t)sA * C + ci * 8);
        uint4 vB = *(const uint4*)(fB + (size_t)sB * C + ci * 8);
        a[0] += bflo(vA.x); a[1] += bfhi(vA.x);
        a[2] += bflo(vA.y); a[3] += bfhi(vA.y);
        a[4] += bflo(vA.z); a[5] += bfhi(vA.z);
        a[6] += bflo(vA.w); a[7] += bfhi(vA.w);
        a[0] += bflo(vB.x); a[1] += bfhi(vB.x);
        a[2] += bflo(vB.y); a[3] += bfhi(vB.y);
        a[4] += bflo(vB.z); a[5] += bfhi(vB.z);
        a[6] += bflo(vB.w); a[7] += bfhi(vB.w);
    }
    for (; j < end; j += 8) {
        if (j + s8 < end) {
            int s = eSrc[j + s8];
            uint4 v = *(const uint4*)(fB + (size_t)s * C + ci * 8);
            a[0] += bflo(v.x); a[1] += bfhi(v.x);
            a[2] += bflo(v.y); a[3] += bfhi(v.y);
            a[4] += bflo(v.z); a[5] += bfhi(v.z);
            a[6] += bflo(v.w); a[7] += bfhi(v.w);
        }
    }
    #pragma unroll
    for (int m = 8; m < 64; m <<= 1)
        #pragma unroll
        for (int k = 0; k < 8; ++k)
            a[k] += __shfl_xor(a[k], m, 64);
    if (s8 == 0) {
        float di = deg_inv[node];
        uint4 o;
        o.x = pack2(a[0] * di, a[1] * di);
        o.y = pack2(a[2] * di, a[3] * di);
        o.z = pack2(a[4] * di, a[5] * di);
        o.w = pack2(a[6] * di, a[7] * di);
        *(uint4*)(aggB + (size_t)node * C + ci * 8) = o;
    }
}

// ---- dense SAGE layer via MFMA: h = relu([agg|x] @ [Wl;Wr] + bl) -----------
__global__ __launch_bounds__(256) void dense_mfma(
        const unsigned short* __restrict__ aB, const unsigned short* __restrict__ xB,
        const float* __restrict__ Wl, const float* __restrict__ Wr,
        const float* __restrict__ bl, unsigned short* __restrict__ hOut, int N) {
    __shared__ unsigned short sW[C * SK];
    __shared__ unsigned short sAB[C * SK];
    int t = threadIdx.x;
    int lane = t & 63, w = t >> 6;
    int l15 = lane & 15, quad = lane >> 4;
    int n0 = blockIdx.x * 64;

    for (int i = t; i < 128 * C; i += 256) {
        int k = i >> 6, n = i & 63;
        float v = (k < C) ? Wl[k * C + n] : Wr[(k - C) * C + n];
        sW[n * SK + k] = f2bf(v);
    }
    for (int i = t; i < 64 * 16; i += 256) {
        int r = i >> 4, ch = i & 15;
        int node = n0 + r;
        uint4 v = {0u, 0u, 0u, 0u};
        if (node < N)
            v = (ch < 8) ? *(const uint4*)(aB + (size_t)node * C + ch * 8)
                         : *(const uint4*)(xB + (size_t)node * C + (ch - 8) * 8);
        *(uint4*)&sAB[r * SK + ch * 8] = v;
    }
    __syncthreads();

    short8 bW[4][4];
    #pragma unroll
    for (int t4 = 0; t4 < 4; ++t4)
        #pragma unroll
        for (int kc = 0; kc < 4; ++kc)
            bW[t4][kc] = *(const short8*)&sW[(t4 * 16 + l15) * SK + kc * 32 + quad * 8];
    float blr[4];
    #pragma unroll
    for (int t4 = 0; t4 < 4; ++t4) blr[t4] = bl[t4 * 16 + l15];

    f32x4 acc[4] = {{0.f, 0.f, 0.f, 0.f}, {0.f, 0.f, 0.f, 0.f},
                    {0.f, 0.f, 0.f, 0.f}, {0.f, 0.f, 0.f, 0.f}};
    #pragma unroll
    for (int kc = 0; kc < 4; ++kc) {
        short8 a = *(const short8*)&sAB[(w * 16 + l15) * SK + kc * 32 + quad * 8];
        #pragma unroll
        for (int t4 = 0; t4 < 4; ++t4)
            acc[t4] = __builtin_amdgcn_mfma_f32_16x16x32_bf16(a, bW[t4][kc], acc[t4], 0, 0, 0);
    }
    __syncthreads();

    #pragma unroll
    for (int t4 = 0; t4 < 4; ++t4)
        #pragma unroll
        for (int r = 0; r < 4; ++r) {
            int rl = w * 16 + quad * 4 + r;
            sW[rl * 72 + t4 * 16 + l15] = f2bf(fmaxf(acc[t4][r] + blr[t4], 0.f));
        }
    __syncthreads();
    for (int i = t; i < 64 * 8; i += 256) {
        int r = i >> 3, c8 = i & 7;
        int node = n0 + r;
        if (node < N)
            *(uint4*)(hOut + (size_t)node * C + c8 * 8) = *(const uint4*)&sW[r * 72 + c8 * 8];
    }
}

// ---- edge MLP: bf16 MFMA, register A-gather, 2-stage pipeline (R7 proven) --
template <bool EAB>
__device__ __forceinline__ void gather_rows(const unsigned short* __restrict__ hB,
        const unsigned short* __restrict__ eaB, const float* __restrict__ ea,
        int s, int d, int idxc, int quad,
        uint4& u0, uint4& u1, uint4& u2, uint4& u3, uint4& u4) {
    const uint4* ps = (const uint4*)(hB + (size_t)s * C);
    const uint4* pd = (const uint4*)(hB + (size_t)d * C);
    u0 = ps[quad];
    u1 = ps[4 + quad];
    u2 = pd[quad];
    u3 = pd[4 + quad];
    u4.x = 0u; u4.y = 0u; u4.z = 0u; u4.w = 0u;
    if (quad < 2) {
        if (EAB) {
            u4 = *(const uint4*)(eaB + (size_t)idxc * 16 + quad * 8);
        } else {
            const float4* pe = (const float4*)(ea + (size_t)idxc * 16 + quad * 8);
            float4 f0 = pe[0], f1 = pe[1];
            u4.x = pack2(f0.x, f0.y); u4.y = pack2(f0.z, f0.w);
            u4.z = pack2(f1.x, f1.y); u4.w = pack2(f1.z, f1.w);
        }
    }
}

template <bool EAB>
__global__ __launch_bounds__(256) void edge_mlp_pipe(
        const unsigned short* __restrict__ hB, const int* __restrict__ src,
        const int* __restrict__ dst, const float* __restrict__ ea,
        const unsigned short* __restrict__ eaB,
        const float* __restrict__ Wm1, const float* __restrict__ bm1,
        const float* __restrict__ Wm2, const float* __restrict__ bm2,
        float* __restrict__ out, int E, int nTiles) {
    __shared__ unsigned short sW[C * KP];     // Wm1^T bf16, K zero-padded to 160
    int t = threadIdx.x;
    int lane = t & 63, w = t >> 6;
    int l15 = lane & 15, quad = lane >> 4;

    for (int i = t; i < C * 3; i += 256) {
        int r = i / 3, cc = 144 + (i % 3) * 8;
        uint4 z = {0u, 0u, 0u, 0u};
        *(uint4*)&sW[r * KP + cc] = z;
    }
    for (int i = t; i < 144 * C; i += 256) {
        int k = i >> 6, n = i & 63;
        sW[n * KP + k] = f2bf(Wm1[i]);
    }
    __syncthreads();

    short8 bW[4][5];
    #pragma unroll
    for (int t4 = 0; t4 < 4; ++t4)
        #pragma unroll
        for (int kc = 0; kc < 5; ++kc)
            bW[t4][kc] = *(const short8*)&sW[(t4 * 16 + l15) * KP + kc * 32 + quad * 8];
    float bmr[4], w2r[4];
    #pragma unroll
    for (int t4 = 0; t4 < 4; ++t4) {
        int j = t4 * 16 + l15;
        bmr[t4] = bm1[j];
        w2r[t4] = Wm2[j];
    }
    float bb = bm2[0];

    int stride = gridDim.x;
    int lbase = w * 16 + l15;

    int tile = blockIdx.x;
    int idxc = min(tile * TILE_E + lbase, E - 1);
    int s = src[idxc], d = dst[idxc];
    int tileN = tile + stride;
    int idxNc = (tileN < nTiles) ? min(tileN * TILE_E + lbase, E - 1) : idxc;
    int sN = src[idxNc], dN = dst[idxNc];
    uint4 cu0, cu1, cu2, cu3, cu4;
    gather_rows<EAB>(hB, eaB, ea, s, d, idxc, quad, cu0, cu1, cu2, cu3, cu4);

    while (true) {
        bool hasNext = (tileN < nTiles);
        uint4 nu0, nu1, nu2, nu3, nu4;
        gather_rows<EAB>(hB, eaB, ea, sN, dN, idxNc, quad, nu0, nu1, nu2, nu3, nu4);
        int tileNN = tileN + stride;
        int idxNNc = (tileNN < nTiles) ? min(tileNN * TILE_E + lbase, E - 1) : idxNc;
        int sNN = src[idxNNc], dNN = dst[idxNNc];

        short8 a0 = *(short8*)&cu0, a1 = *(short8*)&cu1, a2 = *(short8*)&cu2,
               a3 = *(short8*)&cu3, a4 = *(short8*)&cu4;
        f32x4 acc[4] = {{0.f, 0.f, 0.f, 0.f}, {0.f, 0.f, 0.f, 0.f},
                        {0.f, 0.f, 0.f, 0.f}, {0.f, 0.f, 0.f, 0.f}};
        #pragma unroll
        for (int t4 = 0; t4 < 4; ++t4) {
            acc[t4] = __builtin_amdgcn_mfma_f32_16x16x32_bf16(a0, bW[t4][0], acc[t4], 0, 0, 0);
            acc[t4] = __builtin_amdgcn_mfma_f32_16x16x32_bf16(a1, bW[t4][1], acc[t4], 0, 0, 0);
            acc[t4] = __builtin_amdgcn_mfma_f32_16x16x32_bf16(a2, bW[t4][2], acc[t4], 0, 0, 0);
            acc[t4] = __builtin_amdgcn_mfma_f32_16x16x32_bf16(a3, bW[t4][3], acc[t4], 0, 0, 0);
            acc[t4] = __builtin_amdgcn_mfma_f32_16x16x32_bf16(a4, bW[t4][4], acc[t4], 0, 0, 0);
        }

        float sres[4];
        #pragma unroll
        for (int r = 0; r < 4; ++r) {
            float v = 0.f;
            #pragma unroll
            for (int t4 = 0; t4 < 4; ++t4)
                v += fmaxf(acc[t4][r] + bmr[t4], 0.f) * w2r[t4];
            #pragma unroll
            for (int m = 1; m < 16; m <<= 1)
                v += __shfl_xor(v, m, 16);
            sres[r] = v;
        }
        if (l15 == 0) {
            int e0 = tile * TILE_E;
            #pragma unroll
            for (int r = 0; r < 4; ++r) {
                int e = e0 + w * 16 + quad * 4 + r;
                if (e < E) out[e] = sres[r] + bb;
            }
        }

        if (!hasNext) break;
        tile = tileN; tileN = tileNN;
        idxc = idxNc; idxNc = idxNNc;
        s = sN; sN = sNN; d = dN; dN = dNN;
        cu0 = nu0; cu1 = nu1; cu2 = nu2; cu3 = nu3; cu4 = nu4;
    }
}

// ---------------------------------------------------------------------------
extern "C" void kernel_launch(void* const* d_in, const int* in_sizes, int n_in,
                              void* d_out, int out_size, void* d_ws, size_t ws_size,
                              hipStream_t stream) {
    const float* x   = (const float*)d_in[0];
    const int*   ei  = (const int*)d_in[1];
    const float* ea  = (const float*)d_in[2];
    const float* W1l = (const float*)d_in[3];
    const float* b1l = (const float*)d_in[4];
    const float* W1r = (const float*)d_in[5];
    const float* W2l = (const float*)d_in[6];
    const float* b2l = (const float*)d_in[7];
    const float* W2r = (const float*)d_in[8];
    const float* Wm1 = (const float*)d_in[9];
    const float* bm1 = (const float*)d_in[10];
    const float* Wm2 = (const float*)d_in[11];
    const float* bm2 = (const float*)d_in[12];
    float* out = (float*)d_out;

    const int N = in_sizes[0] / C;
    const int E = in_sizes[1] / 2;
    const int* src = ei;
    const int* dst = ei + E;

    char* wsb = (char*)d_ws;
    int npad = (N + 1023) & ~1023;
    float* deg_inv = (float*)wsb;                wsb += (size_t)npad * 4;
    unsigned short* xB   = (unsigned short*)wsb; wsb += (size_t)npad * C * 2;
    unsigned short* h1B  = (unsigned short*)wsb; wsb += (size_t)npad * C * 2;
    unsigned short* h2B  = (unsigned short*)wsb; wsb += (size_t)npad * C * 2;
    unsigned short* aggB = (unsigned short*)wsb; wsb += (size_t)npad * C * 2;
    int* degi    = (int*)wsb;                    wsb += (size_t)npad * 4;
    int* rowptr  = (int*)wsb;                    wsb += (size_t)(npad + 64) * 4;
    int* cursor  = (int*)wsb;                    wsb += (size_t)npad * 4;
    int* eSrc    = (int*)wsb;                    wsb += (size_t)E * 4;
    int* partials = (int*)wsb;                   wsb += 64 * 4;
    unsigned short* eaB = (unsigned short*)wsb;  // E*16 bf16 = 25.6 MB (optional)
    size_t used = (size_t)(wsb - (char*)d_ws);
    int useEaB = (ws_size >= used + (size_t)E * 16 * 2) ? 1 : 0;

    int tpb = 256;
    int nb = (N + 1023) / 1024;
    int nx8 = N * C / 8;

    // CSR build + input converts
    hipMemsetAsync(degi, 0, (size_t)N * sizeof(int), stream);
    int prepN = (2 * E > nx8) ? 2 * E : nx8;
    prep<<<(prepN + tpb - 1) / tpb, tpb, 0, stream>>>(dst, degi, ea, eaB, x, xB, E, nx8, useEaB);
    scan_partial<<<nb, tpb, 0, stream>>>(degi, rowptr, partials, N);
    scan_add_fused<<<(N + tpb - 1) / tpb, tpb, 0, stream>>>(rowptr, partials, cursor,
            degi, deg_inv, N, E, nb);
    fill_csr_xcd<<<2048, tpb, 0, stream>>>(src, dst, cursor, eSrc, E);

    // layer 1
    csr_agg_bf16<<<(N + 3) / 4, tpb, 0, stream>>>(xB, rowptr, eSrc, deg_inv, aggB, N);
    dense_mfma<<<(N + 63) / 64, tpb, 0, stream>>>(aggB, xB, W1l, W1r, b1l, h1B, N);

    // layer 2
    csr_agg_bf16<<<(N + 3) / 4, tpb, 0, stream>>>(h1B, rowptr, eSrc, deg_inv, aggB, N);
    dense_mfma<<<(N + 63) / 64, tpb, 0, stream>>>(aggB, h1B, W2l, W2r, b2l, h2B, N);

    // edge MLP (pipelined, R7 variant)
    int nTiles = (E + TILE_E - 1) / TILE_E;
    int grid = nTiles < 2048 ? nTiles : 2048;
    if (useEaB)
        edge_mlp_pipe<true><<<grid, tpb, 0, stream>>>(h2B, src, dst, ea, eaB,
                Wm1, bm1, Wm2, bm2, out, E, nTiles);
    else
        edge_mlp_pipe<false><<<grid, tpb, 0, stream>>>(h2B, src, dst, ea, eaB,
                Wm1, bm1, Wm2, bm2, out, E, nTiles);
}

// Round 14
// 298.817 us; speedup vs baseline: 1.1340x; 1.0030x over previous
//
#include <hip/hip_runtime.h>
#include <hip/hip_bf16.h>

// ---------------------------------------------------------------------------
// EdgeClassifier: 2-layer GraphSAGE (mean agg) + edge-scoring MLP.
// Full bf16 data path (fp32 accumulate). R14 = R13 (best: 299.7us) with
// csr_agg restructured node-parallel: 8 nodes/wave, lane=(node,ch-group),
// serial per-lane loop over the CSR row -> ~16 loads in flight/lane (vs 2
// per wave in the slot-parallel version; the loop's only carried dep is the
// fp32 accumulator). No butterfly, full uint4 store coverage, ~20 VGPR.
//   prep: deg atomics + ea->bf16 + x->bf16   [eaB: measured win, R12]
//   CSR build: scan + XCD-group-partitioned place (R9: write-amp fix)
//   per layer: csr_agg_np -> dense_mfma (K=128 GEMM)
//   edge_mlp_pipe: R7-proven, VGPR 80 / 6 waves/SIMD (R10: never cap VGPR)
// N=50000, E=800000, C=64, EDGE_DIM=16, MLP K=144 padded to 160.
// ---------------------------------------------------------------------------

#define C 64
#define KP 168          // edge-MLP weight LDS row stride (shorts)
#define SK 136          // dense LDS K-stride (shorts)
#define TILE_E 64
#define WSHIFT 12       // 4096-node dst windows for the fill partition

typedef short short8 __attribute__((ext_vector_type(8)));
typedef float f32x4 __attribute__((ext_vector_type(4)));

__device__ __forceinline__ unsigned short f2bf(float f) {
    unsigned int u = __float_as_uint(f);
    return (unsigned short)((u + 0x7FFFu + ((u >> 16) & 1u)) >> 16);   // RNE
}
__device__ __forceinline__ unsigned int pack2(float lo, float hi) {
    return (unsigned int)f2bf(lo) | ((unsigned int)f2bf(hi) << 16);
}
__device__ __forceinline__ float bflo(unsigned int u) { return __uint_as_float(u << 16); }
__device__ __forceinline__ float bfhi(unsigned int u) { return __uint_as_float(u & 0xFFFF0000u); }

// ---- prep: degree atomics + ea->bf16 + x->bf16, one kernel -----------------
__global__ void prep(const int* __restrict__ dst, int* __restrict__ degi,
                     const float* __restrict__ ea, unsigned short* __restrict__ eaB,
                     const float* __restrict__ x, unsigned short* __restrict__ xB,
                     int E, int nx8, int doEa) {
    int i = blockIdx.x * blockDim.x + threadIdx.x;
    if (i < E) atomicAdd(&degi[dst[i]], 1);
    if (doEa && i < 2 * E) {
        const float4* p = (const float4*)(ea + (size_t)i * 8);
        float4 a = p[0], b = p[1];
        uint4 o;
        o.x = pack2(a.x, a.y); o.y = pack2(a.z, a.w);
        o.z = pack2(b.x, b.y); o.w = pack2(b.z, b.w);
        *(uint4*)(eaB + (size_t)i * 8) = o;
    }
    if (i < nx8) {
        const float4* p = (const float4*)(x + (size_t)i * 8);
        float4 a = p[0], b = p[1];
        uint4 o;
        o.x = pack2(a.x, a.y); o.y = pack2(a.z, a.w);
        o.z = pack2(b.x, b.y); o.w = pack2(b.z, b.w);
        *(uint4*)(xB + (size_t)i * 8) = o;
    }
}

// ---- CSR build --------------------------------------------------------------
__global__ __launch_bounds__(256) void scan_partial(const int* __restrict__ degi,
        int* __restrict__ rowptr, int* __restrict__ partials, int N) {
    __shared__ int sWs[4];
    int t = threadIdx.x, b = blockIdx.x;
    int g0 = b * 1024 + t * 4;
    int v0 = (g0 + 0 < N) ? degi[g0 + 0] : 0;
    int v1 = (g0 + 1 < N) ? degi[g0 + 1] : 0;
    int v2 = (g0 + 2 < N) ? degi[g0 + 2] : 0;
    int v3 = (g0 + 3 < N) ? degi[g0 + 3] : 0;
    int tsum = v0 + v1 + v2 + v3;
    int lane = t & 63, w = t >> 6;
    int incl = tsum;
    #pragma unroll
    for (int m = 1; m < 64; m <<= 1) {
        int y = __shfl_up(incl, m, 64);
        if (lane >= m) incl += y;
    }
    if (lane == 63) sWs[w] = incl;
    __syncthreads();
    int wprefix = 0;
    for (int i = 0; i < w; ++i) wprefix += sWs[i];
    int run = wprefix + incl - tsum;
    if (g0 + 0 < N) rowptr[g0 + 0] = run; run += v0;
    if (g0 + 1 < N) rowptr[g0 + 1] = run; run += v1;
    if (g0 + 2 < N) rowptr[g0 + 2] = run; run += v2;
    if (g0 + 3 < N) rowptr[g0 + 3] = run;
    if (t == 255) partials[b] = wprefix + incl;
}

__global__ __launch_bounds__(256) void scan_add_fused(int* __restrict__ rowptr,
        const int* __restrict__ partials, int* __restrict__ cursor,
        const int* __restrict__ degi, float* __restrict__ deg_inv,
        int N, int E, int nb) {
    __shared__ int sOff[64];
    int t = threadIdx.x;
    if (t < 64) {
        int v = (t < nb) ? partials[t] : 0;
        int incl = v;
        #pragma unroll
        for (int m = 1; m < 64; m <<= 1) {
            int y = __shfl_up(incl, m, 64);
            if (t >= m) incl += y;
        }
        sOff[t] = incl - v;
    }
    __syncthreads();
    int i = blockIdx.x * 256 + t;
    if (i < N) {
        int r = rowptr[i] + sOff[i >> 10];
        rowptr[i] = r;
        cursor[i] = r;
        deg_inv[i] = 1.0f / fmaxf((float)degi[i], 1.0f);
    }
    if (i == 0) rowptr[N] = E;
}

// XCD-group-partitioned place (R9 proven: killed the write amplification).
__global__ __launch_bounds__(256) void fill_csr_xcd(const int* __restrict__ src,
        const int* __restrict__ dst, int* __restrict__ cursor,
        int* __restrict__ eSrc, int E) {
    int g = blockIdx.x & 7;
    int tid = (blockIdx.x >> 3) * 256 + threadIdx.x;
    int stride = (gridDim.x >> 3) * 256;
    for (int e = tid; e < E; e += stride) {
        int d = dst[e];
        if (((d >> WSHIFT) & 7) == g) {
            int pos = atomicAdd(&cursor[d], 1);
            eSrc[pos] = src[e];
        }
    }
}

// ---- CSR gather mean-aggregation, node-parallel (R14) ----------------------
// 8 nodes per wave: lane = (nl=lane&7 node) x (cg=lane>>3 ch-group of 8).
// Each lane loops its node's CSR row; loads pipeline across iterations
// (only the fp32 accumulator is loop-carried). 8 lanes/node share eSrc[j]
// reads (HW broadcast). Stores: 8 nodes x 8 cg = 64 uint4, full coverage.
__global__ __launch_bounds__(256) void csr_agg_np(const unsigned short* __restrict__ fB,
        const int* __restrict__ rowptr, const int* __restrict__ eSrc,
        const float* __restrict__ deg_inv, unsigned short* __restrict__ aggB, int N) {
    int wv = threadIdx.x >> 6;
    int lane = threadIdx.x & 63;
    int nl = lane & 7, cg = lane >> 3;
    int node = blockIdx.x * 32 + wv * 8 + nl;
    if (node >= N) return;
    int row = rowptr[node], end = rowptr[node + 1];
    float a[8] = {0.f, 0.f, 0.f, 0.f, 0.f, 0.f, 0.f, 0.f};
    int j = row;
    for (; j + 2 <= end; j += 2) {       // 2-way unroll: 4 loads in flight/iter
        int s0 = eSrc[j];
        int s1 = eSrc[j + 1];
        uint4 v0 = *(const uint4*)(fB + (size_t)s0 * C + cg * 8);
        uint4 v1 = *(const uint4*)(fB + (size_t)s1 * C + cg * 8);
        a[0] += bflo(v0.x); a[1] += bfhi(v0.x);
        a[2] += bflo(v0.y); a[3] += bfhi(v0.y);
        a[4] += bflo(v0.z); a[5] += bfhi(v0.z);
        a[6] += bflo(v0.w); a[7] += bfhi(v0.w);
        a[0] += bflo(v1.x); a[1] += bfhi(v1.x);
        a[2] += bflo(v1.y); a[3] += bfhi(v1.y);
        a[4] += bflo(v1.z); a[5] += bfhi(v1.z);
        a[6] += bflo(v1.w); a[7] += bfhi(v1.w);
    }
    if (j < end) {
        int s = eSrc[j];
        uint4 v = *(const uint4*)(fB + (size_t)s * C + cg * 8);
        a[0] += bflo(v.x); a[1] += bfhi(v.x);
        a[2] += bflo(v.y); a[3] += bfhi(v.y);
        a[4] += bflo(v.z); a[5] += bfhi(v.z);
        a[6] += bflo(v.w); a[7] += bfhi(v.w);
    }
    float di = deg_inv[node];
    uint4 o;
    o.x = pack2(a[0] * di, a[1] * di);
    o.y = pack2(a[2] * di, a[3] * di);
    o.z = pack2(a[4] * di, a[5] * di);
    o.w = pack2(a[6] * di, a[7] * di);
    *(uint4*)(aggB + (size_t)node * C + cg * 8) = o;
}

// ---- dense SAGE layer via MFMA: h = relu([agg|x] @ [Wl;Wr] + bl) -----------
__global__ __launch_bounds__(256) void dense_mfma(
        const unsigned short* __restrict__ aB, const unsigned short* __restrict__ xB,
        const float* __restrict__ Wl, const float* __restrict__ Wr,
        const float* __restrict__ bl, unsigned short* __restrict__ hOut, int N) {
    __shared__ unsigned short sW[C * SK];
    __shared__ unsigned short sAB[C * SK];
    int t = threadIdx.x;
    int lane = t & 63, w = t >> 6;
    int l15 = lane & 15, quad = lane >> 4;
    int n0 = blockIdx.x * 64;

    for (int i = t; i < 128 * C; i += 256) {
        int k = i >> 6, n = i & 63;
        float v = (k < C) ? Wl[k * C + n] : Wr[(k - C) * C + n];
        sW[n * SK + k] = f2bf(v);
    }
    for (int i = t; i < 64 * 16; i += 256) {
        int r = i >> 4, ch = i & 15;
        int node = n0 + r;
        uint4 v = {0u, 0u, 0u, 0u};
        if (node < N)
            v = (ch < 8) ? *(const uint4*)(aB + (size_t)node * C + ch * 8)
                         : *(const uint4*)(xB + (size_t)node * C + (ch - 8) * 8);
        *(uint4*)&sAB[r * SK + ch * 8] = v;
    }
    __syncthreads();

    short8 bW[4][4];
    #pragma unroll
    for (int t4 = 0; t4 < 4; ++t4)
        #pragma unroll
        for (int kc = 0; kc < 4; ++kc)
            bW[t4][kc] = *(const short8*)&sW[(t4 * 16 + l15) * SK + kc * 32 + quad * 8];
    float blr[4];
    #pragma unroll
    for (int t4 = 0; t4 < 4; ++t4) blr[t4] = bl[t4 * 16 + l15];

    f32x4 acc[4] = {{0.f, 0.f, 0.f, 0.f}, {0.f, 0.f, 0.f, 0.f},
                    {0.f, 0.f, 0.f, 0.f}, {0.f, 0.f, 0.f, 0.f}};
    #pragma unroll
    for (int kc = 0; kc < 4; ++kc) {
        short8 a = *(const short8*)&sAB[(w * 16 + l15) * SK + kc * 32 + quad * 8];
        #pragma unroll
        for (int t4 = 0; t4 < 4; ++t4)
            acc[t4] = __builtin_amdgcn_mfma_f32_16x16x32_bf16(a, bW[t4][kc], acc[t4], 0, 0, 0);
    }
    __syncthreads();

    #pragma unroll
    for (int t4 = 0; t4 < 4; ++t4)
        #pragma unroll
        for (int r = 0; r < 4; ++r) {
            int rl = w * 16 + quad * 4 + r;
            sW[rl * 72 + t4 * 16 + l15] = f2bf(fmaxf(acc[t4][r] + blr[t4], 0.f));
        }
    __syncthreads();
    for (int i = t; i < 64 * 8; i += 256) {
        int r = i >> 3, c8 = i & 7;
        int node = n0 + r;
        if (node < N)
            *(uint4*)(hOut + (size_t)node * C + c8 * 8) = *(const uint4*)&sW[r * 72 + c8 * 8];
    }
}

// ---- edge MLP: bf16 MFMA, register A-gather, 2-stage pipeline (R7 proven) --
template <bool EAB>
__device__ __forceinline__ void gather_rows(const unsigned short* __restrict__ hB,
        const unsigned short* __restrict__ eaB, const float* __restrict__ ea,
        int s, int d, int idxc, int quad,
        uint4& u0, uint4& u1, uint4& u2, uint4& u3, uint4& u4) {
    const uint4* ps = (const uint4*)(hB + (size_t)s * C);
    const uint4* pd = (const uint4*)(hB + (size_t)d * C);
    u0 = ps[quad];
    u1 = ps[4 + quad];
    u2 = pd[quad];
    u3 = pd[4 + quad];
    u4.x = 0u; u4.y = 0u; u4.z = 0u; u4.w = 0u;
    if (quad < 2) {
        if (EAB) {
            u4 = *(const uint4*)(eaB + (size_t)idxc * 16 + quad * 8);
        } else {
            const float4* pe = (const float4*)(ea + (size_t)idxc * 16 + quad * 8);
            float4 f0 = pe[0], f1 = pe[1];
            u4.x = pack2(f0.x, f0.y); u4.y = pack2(f0.z, f0.w);
            u4.z = pack2(f1.x, f1.y); u4.w = pack2(f1.z, f1.w);
        }
    }
}

template <bool EAB>
__global__ __launch_bounds__(256) void edge_mlp_pipe(
        const unsigned short* __restrict__ hB, const int* __restrict__ src,
        const int* __restrict__ dst, const float* __restrict__ ea,
        const unsigned short* __restrict__ eaB,
        const float* __restrict__ Wm1, const float* __restrict__ bm1,
        const float* __restrict__ Wm2, const float* __restrict__ bm2,
        float* __restrict__ out, int E, int nTiles) {
    __shared__ unsigned short sW[C * KP];     // Wm1^T bf16, K zero-padded to 160
    int t = threadIdx.x;
    int lane = t & 63, w = t >> 6;
    int l15 = lane & 15, quad = lane >> 4;

    for (int i = t; i < C * 3; i += 256) {
        int r = i / 3, cc = 144 + (i % 3) * 8;
        uint4 z = {0u, 0u, 0u, 0u};
        *(uint4*)&sW[r * KP + cc] = z;
    }
    for (int i = t; i < 144 * C; i += 256) {
        int k = i >> 6, n = i & 63;
        sW[n * KP + k] = f2bf(Wm1[i]);
    }
    __syncthreads();

    short8 bW[4][5];
    #pragma unroll
    for (int t4 = 0; t4 < 4; ++t4)
        #pragma unroll
        for (int kc = 0; kc < 5; ++kc)
            bW[t4][kc] = *(const short8*)&sW[(t4 * 16 + l15) * KP + kc * 32 + quad * 8];
    float bmr[4], w2r[4];
    #pragma unroll
    for (int t4 = 0; t4 < 4; ++t4) {
        int j = t4 * 16 + l15;
        bmr[t4] = bm1[j];
        w2r[t4] = Wm2[j];
    }
    float bb = bm2[0];

    int stride = gridDim.x;
    int lbase = w * 16 + l15;

    int tile = blockIdx.x;
    int idxc = min(tile * TILE_E + lbase, E - 1);
    int s = src[idxc], d = dst[idxc];
    int tileN = tile + stride;
    int idxNc = (tileN < nTiles) ? min(tileN * TILE_E + lbase, E - 1) : idxc;
    int sN = src[idxNc], dN = dst[idxNc];
    uint4 cu0, cu1, cu2, cu3, cu4;
    gather_rows<EAB>(hB, eaB, ea, s, d, idxc, quad, cu0, cu1, cu2, cu3, cu4);

    while (true) {
        bool hasNext = (tileN < nTiles);
        uint4 nu0, nu1, nu2, nu3, nu4;
        gather_rows<EAB>(hB, eaB, ea, sN, dN, idxNc, quad, nu0, nu1, nu2, nu3, nu4);
        int tileNN = tileN + stride;
        int idxNNc = (tileNN < nTiles) ? min(tileNN * TILE_E + lbase, E - 1) : idxNc;
        int sNN = src[idxNNc], dNN = dst[idxNNc];

        short8 a0 = *(short8*)&cu0, a1 = *(short8*)&cu1, a2 = *(short8*)&cu2,
               a3 = *(short8*)&cu3, a4 = *(short8*)&cu4;
        f32x4 acc[4] = {{0.f, 0.f, 0.f, 0.f}, {0.f, 0.f, 0.f, 0.f},
                        {0.f, 0.f, 0.f, 0.f}, {0.f, 0.f, 0.f, 0.f}};
        #pragma unroll
        for (int t4 = 0; t4 < 4; ++t4) {
            acc[t4] = __builtin_amdgcn_mfma_f32_16x16x32_bf16(a0, bW[t4][0], acc[t4], 0, 0, 0);
            acc[t4] = __builtin_amdgcn_mfma_f32_16x16x32_bf16(a1, bW[t4][1], acc[t4], 0, 0, 0);
            acc[t4] = __builtin_amdgcn_mfma_f32_16x16x32_bf16(a2, bW[t4][2], acc[t4], 0, 0, 0);
            acc[t4] = __builtin_amdgcn_mfma_f32_16x16x32_bf16(a3, bW[t4][3], acc[t4], 0, 0, 0);
            acc[t4] = __builtin_amdgcn_mfma_f32_16x16x32_bf16(a4, bW[t4][4], acc[t4], 0, 0, 0);
        }

        float sres[4];
        #pragma unroll
        for (int r = 0; r < 4; ++r) {
            float v = 0.f;
            #pragma unroll
            for (int t4 = 0; t4 < 4; ++t4)
                v += fmaxf(acc[t4][r] + bmr[t4], 0.f) * w2r[t4];
            #pragma unroll
            for (int m = 1; m < 16; m <<= 1)
                v += __shfl_xor(v, m, 16);
            sres[r] = v;
        }
        if (l15 == 0) {
            int e0 = tile * TILE_E;
            #pragma unroll
            for (int r = 0; r < 4; ++r) {
                int e = e0 + w * 16 + quad * 4 + r;
                if (e < E) out[e] = sres[r] + bb;
            }
        }

        if (!hasNext) break;
        tile = tileN; tileN = tileNN;
        idxc = idxNc; idxNc = idxNNc;
        s = sN; sN = sNN; d = dN; dN = dNN;
        cu0 = nu0; cu1 = nu1; cu2 = nu2; cu3 = nu3; cu4 = nu4;
    }
}

// ---------------------------------------------------------------------------
extern "C" void kernel_launch(void* const* d_in, const int* in_sizes, int n_in,
                              void* d_out, int out_size, void* d_ws, size_t ws_size,
                              hipStream_t stream) {
    const float* x   = (const float*)d_in[0];
    const int*   ei  = (const int*)d_in[1];
    const float* ea  = (const float*)d_in[2];
    const float* W1l = (const float*)d_in[3];
    const float* b1l = (const float*)d_in[4];
    const float* W1r = (const float*)d_in[5];
    const float* W2l = (const float*)d_in[6];
    const float* b2l = (const float*)d_in[7];
    const float* W2r = (const float*)d_in[8];
    const float* Wm1 = (const float*)d_in[9];
    const float* bm1 = (const float*)d_in[10];
    const float* Wm2 = (const float*)d_in[11];
    const float* bm2 = (const float*)d_in[12];
    float* out = (float*)d_out;

    const int N = in_sizes[0] / C;
    const int E = in_sizes[1] / 2;
    const int* src = ei;
    const int* dst = ei + E;

    char* wsb = (char*)d_ws;
    int npad = (N + 1023) & ~1023;
    float* deg_inv = (float*)wsb;                wsb += (size_t)npad * 4;
    unsigned short* xB   = (unsigned short*)wsb; wsb += (size_t)npad * C * 2;
    unsigned short* h1B  = (unsigned short*)wsb; wsb += (size_t)npad * C * 2;
    unsigned short* h2B  = (unsigned short*)wsb; wsb += (size_t)npad * C * 2;
    unsigned short* aggB = (unsigned short*)wsb; wsb += (size_t)npad * C * 2;
    int* degi    = (int*)wsb;                    wsb += (size_t)npad * 4;
    int* rowptr  = (int*)wsb;                    wsb += (size_t)(npad + 64) * 4;
    int* cursor  = (int*)wsb;                    wsb += (size_t)npad * 4;
    int* eSrc    = (int*)wsb;                    wsb += (size_t)E * 4;
    int* partials = (int*)wsb;                   wsb += 64 * 4;
    unsigned short* eaB = (unsigned short*)wsb;  // E*16 bf16 = 25.6 MB (optional)
    size_t used = (size_t)(wsb - (char*)d_ws);
    int useEaB = (ws_size >= used + (size_t)E * 16 * 2) ? 1 : 0;

    int tpb = 256;
    int nb = (N + 1023) / 1024;
    int nx8 = N * C / 8;

    // CSR build + input converts
    hipMemsetAsync(degi, 0, (size_t)N * sizeof(int), stream);
    int prepN = (2 * E > nx8) ? 2 * E : nx8;
    prep<<<(prepN + tpb - 1) / tpb, tpb, 0, stream>>>(dst, degi, ea, eaB, x, xB, E, nx8, useEaB);
    scan_partial<<<nb, tpb, 0, stream>>>(degi, rowptr, partials, N);
    scan_add_fused<<<(N + tpb - 1) / tpb, tpb, 0, stream>>>(rowptr, partials, cursor,
            degi, deg_inv, N, E, nb);
    fill_csr_xcd<<<2048, tpb, 0, stream>>>(src, dst, cursor, eSrc, E);

    // layer 1
    int aggGrid = (N + 31) / 32;
    csr_agg_np<<<aggGrid, tpb, 0, stream>>>(xB, rowptr, eSrc, deg_inv, aggB, N);
    dense_mfma<<<(N + 63) / 64, tpb, 0, stream>>>(aggB, xB, W1l, W1r, b1l, h1B, N);

    // layer 2
    csr_agg_np<<<aggGrid, tpb, 0, stream>>>(h1B, rowptr, eSrc, deg_inv, aggB, N);
    dense_mfma<<<(N + 63) / 64, tpb, 0, stream>>>(aggB, h1B, W2l, W2r, b2l, h2B, N);

    // edge MLP (pipelined, R7 variant)
    int nTiles = (E + TILE_E - 1) / TILE_E;
    int grid = nTiles < 2048 ? nTiles : 2048;
    if (useEaB)
        edge_mlp_pipe<true><<<grid, tpb, 0, stream>>>(h2B, src, dst, ea, eaB,
                Wm1, bm1, Wm2, bm2, out, E, nTiles);
    else
        edge_mlp_pipe<false><<<grid, tpb, 0, stream>>>(h2B, src, dst, ea, eaB,
                Wm1, bm1, Wm2, bm2, out, E, nTiles);
}